// Round 9
// baseline (30.503 us; speedup 1.0000x reference)
//
#include <hip/hip_runtime.h>
#include <hip/hip_bf16.h>

typedef __attribute__((ext_vector_type(8))) short short8_t;
typedef __attribute__((ext_vector_type(4))) float f32x4;

static __device__ __forceinline__ unsigned short f2bf(float f) {
    unsigned int u = __float_as_uint(f);
    unsigned int r = u + 0x7fffu + ((u >> 16) & 1u);   // RNE (finite inputs)
    return (unsigned short)(r >> 16);
}

// Convert f32 [rows_valid][128] -> bf16 [rows_total][128] (zero-padded), plus f32 row norms.
__global__ __launch_bounds__(256) void prep_kernel(
        const float* __restrict__ src, unsigned short* __restrict__ dst,
        float* __restrict__ sq, int rows_valid, int rows_total) {
    int t = threadIdx.x;
    int row = blockIdx.x * 8 + (t >> 5);
    int lane32 = t & 31;
    if (row >= rows_total) return;
    float4 v = make_float4(0.f, 0.f, 0.f, 0.f);
    if (row < rows_valid)
        v = reinterpret_cast<const float4*>(src + (size_t)row * 128)[lane32];
    ushort4 b;
    b.x = f2bf(v.x); b.y = f2bf(v.y); b.z = f2bf(v.z); b.w = f2bf(v.w);
    reinterpret_cast<ushort4*>(dst + (size_t)row * 128)[lane32] = b;
    float s = v.x*v.x + v.y*v.y + v.z*v.z + v.w*v.w;
    #pragma unroll
    for (int m = 16; m >= 1; m >>= 1) s += __shfl_xor(s, m, 64);
    if (lane32 == 0) sq[row] = s;
}

#define LDA 136   // 272B LDS row stride -> 2-way bank aliasing on frag reads (free, m136)

// BM=64 x BN=128 tile. 1024 blocks (3/CU), 256 threads. bf16 inputs pre-converted.
// out[m][c] = 2*dot - xsq - psq, nontemporal stores (output never re-read).
__global__ __launch_bounds__(256) void gemm_kernel(
        const unsigned short* __restrict__ Xb,   // [8192][128] bf16 bits
        const unsigned short* __restrict__ Pb,   // [1024][128] bf16 bits (padded)
        const float* __restrict__ xsq,           // [8192]
        const float* __restrict__ psq,           // [1024] (pad rows = 0)
        float* __restrict__ out) {               // [8192][1000] f32
    __shared__ unsigned short As[64][LDA];
    __shared__ unsigned short Bs[128][LDA];
    __shared__ float xq_s[64];
    __shared__ float pq_s[128];

    const int t = threadIdx.x;
    // XCD-chunked swizzle: xcd = wg&7. Each XCD's 128 blocks cover
    // bm in [xcd*16, xcd*16+16) x all 8 bn -> unique A 256KB + B 256KB per XCD L2.
    const int wg  = blockIdx.x;
    const int idx = wg >> 3;
    const int bm  = (wg & 7) * 16 + (idx >> 3);   // 0..127
    const int bn  = idx & 7;                       // 0..7
    const int rowA0 = bm * 64;
    const int rowB0 = bn * 128;

    // ---- stage A: 64 rows x 128 bf16 (16KB), 4 threads/row x 64B ----
    {
        int r = t >> 2, c0 = (t & 3) * 32;
        const short8_t* src = reinterpret_cast<const short8_t*>(
                Xb + (size_t)(rowA0 + r) * 128 + c0);
        short8_t v0 = src[0], v1 = src[1], v2 = src[2], v3 = src[3];
        short8_t* dst = reinterpret_cast<short8_t*>(&As[r][c0]);
        dst[0] = v0; dst[1] = v1; dst[2] = v2; dst[3] = v3;
    }
    // ---- stage B: 128 rows x 128 bf16 (32KB), 2 threads/row x 128B ----
    {
        int r = t >> 1, c0 = (t & 1) * 64;
        const short8_t* src = reinterpret_cast<const short8_t*>(
                Pb + (size_t)(rowB0 + r) * 128 + c0);
        short8_t v0 = src[0], v1 = src[1], v2 = src[2], v3 = src[3];
        short8_t v4 = src[4], v5 = src[5], v6 = src[6], v7 = src[7];
        short8_t* dst = reinterpret_cast<short8_t*>(&Bs[r][c0]);
        dst[0] = v0; dst[1] = v1; dst[2] = v2; dst[3] = v3;
        dst[4] = v4; dst[5] = v5; dst[6] = v6; dst[7] = v7;
    }
    if (t < 64)  xq_s[t] = xsq[rowA0 + t];
    if (t < 128) pq_s[t] = psq[rowB0 + t];
    __syncthreads();

    const int wave = t >> 6;
    const int lane = t & 63;
    const int wm = (wave >> 1) * 32;     // 0 / 32
    const int wn = (wave & 1) * 64;      // 0 / 64
    const int lr = lane & 15;
    const int lkb = (lane >> 4) * 8;
    const int rbase = (lane >> 4) * 4;

    f32x4 acc[2][4] = {};
    #pragma unroll
    for (int ks = 0; ks < 4; ++ks) {
        int k0 = ks * 32 + lkb;
        short8_t a[2], b[4];
        #pragma unroll
        for (int mi = 0; mi < 2; ++mi)
            a[mi] = *reinterpret_cast<const short8_t*>(&As[wm + mi * 16 + lr][k0]);
        #pragma unroll
        for (int ni = 0; ni < 4; ++ni)
            b[ni] = *reinterpret_cast<const short8_t*>(&Bs[wn + ni * 16 + lr][k0]);
        #pragma unroll
        for (int mi = 0; mi < 2; ++mi)
            #pragma unroll
            for (int ni = 0; ni < 4; ++ni)
                acc[mi][ni] = __builtin_amdgcn_mfma_f32_16x16x32_bf16(
                        a[mi], b[ni], acc[mi][ni], 0, 0, 0);
    }

    // Epilogue: C/D layout col=lane&15, row=(lane>>4)*4+j  [m89].
    // Nontemporal: output is write-once, keep it out of L2.
    #pragma unroll
    for (int mi = 0; mi < 2; ++mi) {
        #pragma unroll
        for (int ni = 0; ni < 4; ++ni) {
            int cl = wn + ni * 16 + lr;
            int c = rowB0 + cl;
            if (c < 1000) {
                float pq = pq_s[cl];
                #pragma unroll
                for (int j = 0; j < 4; ++j) {
                    int ml = wm + mi * 16 + rbase + j;
                    float v = 2.f * acc[mi][ni][j] - xq_s[ml] - pq;
                    __builtin_nontemporal_store(v, out + (size_t)(rowA0 + ml) * 1000 + c);
                }
            }
        }
    }
}

// Correct-but-slow fallback.
__global__ __launch_bounds__(256) void naive_kernel(
        const float* __restrict__ x, const float* __restrict__ p,
        float* __restrict__ out) {
    long long idx = (long long)blockIdx.x * 256 + threadIdx.x;
    if (idx >= (long long)8192 * 1000) return;
    int n = (int)(idx / 1000);
    int c = (int)(idx % 1000);
    const float4* xr = reinterpret_cast<const float4*>(x + (size_t)n * 128);
    const float4* pr = reinterpret_cast<const float4*>(p + (size_t)c * 128);
    float d = 0.f;
    #pragma unroll
    for (int i = 0; i < 32; ++i) {
        float4 a = xr[i], b = pr[i];
        float dx = a.x - b.x, dy = a.y - b.y, dz = a.z - b.z, dw = a.w - b.w;
        d += dx * dx + dy * dy + dz * dz + dw * dw;
    }
    out[idx] = -d;
}

extern "C" void kernel_launch(void* const* d_in, const int* in_sizes, int n_in,
                              void* d_out, int out_size, void* d_ws, size_t ws_size,
                              hipStream_t stream) {
    const float* x = (const float*)d_in[0];   // (8192, 128) f32
    const float* p = (const float*)d_in[1];   // (1000, 128) f32
    float* out = (float*)d_out;               // (8192, 1000) f32

    const size_t xb_elems = (size_t)8192 * 128;
    const size_t pb_elems = (size_t)1024 * 128;
    const size_t need = xb_elems * 2 + pb_elems * 2 + 8192 * 4 + 1024 * 4;

    if (ws_size >= need) {
        unsigned short* xb = (unsigned short*)d_ws;
        unsigned short* pb = xb + xb_elems;
        float* xsq = (float*)(pb + pb_elems);
        float* psq = xsq + 8192;
        prep_kernel<<<1024, 256, 0, stream>>>(x, xb, xsq, 8192, 8192);
        prep_kernel<<<128, 256, 0, stream>>>(p, pb, psq, 1000, 1024);
        gemm_kernel<<<1024, 256, 0, stream>>>(xb, pb, xsq, psq, out);
    } else {
        naive_kernel<<<((size_t)8192 * 1000 + 255) / 256, 256, 0, stream>>>(x, p, out);
    }
}